// Round 5
// baseline (508.284 us; speedup 1.0000x reference)
//
#include <hip/hip_runtime.h>
#include <hip/hip_bf16.h>

// RWKV7 WKV chunked scan. T=4096, H=32, N=64. Output fp32 (y then S_final).
//
// Pass 1 (R9): FOUR waves per (chunk, head), column-split 16 cols/wave for
//   BOTH the P scan and the M scan. Per step each wave computes partial
//   sa = S_row.a over its 16 columns; 4 partials summed via double-buffered
//   LDS with ONE barrier per step. y/q output dots are deferred one step and
//   share the same barrier (wv0 finalizes y, wv1 finalizes rho). Broadcasts
//   are readlane with inline-constant lane index 0..15. Rationale: reported
//   VALUBusy is ~2x real (gfx94x 4-cyc formula vs CDNA4 2-cyc SIMD-32), so
//   R5's "77%" was ~38% real -> latency-bound; 8 waves/SIMD doubles hiding.
// Pass 2 (R9): wave = row r, lane = col j, S in registers, k-dot broadcasts
//   S[r][k] via readlane. M staged per chunk through LDS (stride 68, b128
//   conflict-free), double-buffered, one barrier/chunk. P now ALSO staged via
//   LDS (lpp): the old direct Pt[j*64+r] read was 64-line address-divergent
//   per instruction; staged read is 8 lines/wave.
// Pass 3 (R8): S_before tile staged through LDS (pad 68), Srow via b128;
//   rho rows coalesced + readlane; y RMW coalesced.

#define Tt 4096
#define Hh 32
#define Nn 64
#define Ll 64              // chunk length
#define Cc 64              // number of chunks
#define HN (Hh * Nn)       // 2048
#define NN (Nn * Nn)       // 4096

__device__ __forceinline__ float ldf(const float* p) { return *p; }
__device__ __forceinline__ float ldf(const __hip_bfloat16* p) { return __bfloat162float(*p); }
__device__ __forceinline__ void stf(float* p, float v) { *p = v; }
__device__ __forceinline__ void stf(__hip_bfloat16* p, float v) { *p = __float2bfloat16(v); }

__device__ __forceinline__ float rl(float v, int j) {
    return __int_as_float(__builtin_amdgcn_readlane(__float_as_int(v), j));
}

// unpack a uint (2 bf16) into two floats, elem0 = low 16 bits
__device__ __forceinline__ float bflo(unsigned u) { return __uint_as_float(u << 16); }
__device__ __forceinline__ float bfhi(unsigned u) { return __uint_as_float(u & 0xffff0000u); }

// ---------------------------------------------------------------- pass 1
template <typename ST>
__global__ __launch_bounds__(256, 8)
void pass1_scan(const float* __restrict__ rr, const float* __restrict__ ww,
                const float* __restrict__ kk, const float* __restrict__ vv,
                const float* __restrict__ aa, const float* __restrict__ bb,
                float* __restrict__ ylocal,
                ST* __restrict__ rho, ST* __restrict__ Mt, ST* __restrict__ Pt)
{
    const int c    = blockIdx.x >> 5;      // chunk
    const int h    = blockIdx.x & 31;      // head
    const int tid  = threadIdx.x;
    const int lane = tid & 63;             // row i
    const int wv   = tid >> 6;             // column-quarter 0..3
    const int j0   = __builtin_amdgcn_readfirstlane(wv << 4);

    // partial-exchange buffers, double-buffered over step parity
    __shared__ float2 ex1[2][4][64];       // [par][wave][row] = {saP, saM} partials
    __shared__ float  exy[2][4][64];       // [par][wave][row] = y partial (wv0 finalizes)
    __shared__ float  exq[2][4][64];       // [par][wave][row] = q partial (wv1 finalizes)

    float SP[16];                          // P scan, local columns
    float SM[16];                          // M scan, local columns
    #pragma unroll
    for (int jj = 0; jj < 16; ++jj) {
        SP[jj] = 0.0f;
        SM[jj] = (j0 + jj == lane) ? 1.0f : 0.0f;
    }

    int base = (c * Ll * Hh + h) * Nn;     // element offset of step t
    const int lv = j0 + (lane & 15);       // broadcast-source element this lane carries
    float ca = aa[base + lv];
    float cw = ww[base + lv];
    float cb = bb[base + lv];
    float cr = rr[base + lv];
    float ck = kk[base + lv];
    float cv = vv[base + lane];            // per-row value (full vector per lane)

    float py = 0.f, pq = 0.f;              // y/q partials of step t-1 (exchanged next iter)

    for (int t = 0; t < Ll; ++t) {
        // partial sa over local 16 columns (shared a broadcasts between both scans)
        float p0 = 0.f, p1 = 0.f, m0 = 0.f, m1 = 0.f;
        #pragma unroll
        for (int jj = 0; jj < 16; jj += 2) {
            const float a0 = rl(ca, jj), a1 = rl(ca, jj + 1);
            p0 += SP[jj + 0] * a0;  m0 += SM[jj + 0] * a0;
            p1 += SP[jj + 1] * a1;  m1 += SM[jj + 1] * a1;
        }
        const float pP = p0 + p1, pM = m0 + m1;

        ex1[t & 1][wv][lane] = make_float2(pP, pM);
        if (t > 0) {
            exy[(t - 1) & 1][wv][lane] = py;
            exq[(t - 1) & 1][wv][lane] = pq;
        }
        __syncthreads();
        const float2 e0 = ex1[t & 1][0][lane];
        const float2 e1 = ex1[t & 1][1][lane];
        const float2 e2 = ex1[t & 1][2][lane];
        const float2 e3 = ex1[t & 1][3][lane];
        const float saP = (e0.x + e1.x) + (e2.x + e3.x);
        const float saM = (e0.y + e1.y) + (e2.y + e3.y);
        if (t > 0) {                        // finish + store step t-1 outputs
            const int p = (t - 1) & 1;
            const int ob = base - HN + lane;
            if (wv == 0) {
                ylocal[ob] = (exy[p][0][lane] + exy[p][1][lane])
                           + (exy[p][2][lane] + exy[p][3][lane]);
            } else if (wv == 1) {
                stf(&rho[ob], (exq[p][0][lane] + exq[p][1][lane])
                            + (exq[p][2][lane] + exq[p][3][lane]));
            }
        }

        // prefetch next step's vectors (uniform branch; hides under update loop)
        float na = 0.f, nw = 0.f, nb = 0.f, nr = 0.f, nk = 0.f, nv = 0.f;
        if (t + 1 < Ll) {
            const int b2 = base + HN;
            na = aa[b2 + lv]; nw = ww[b2 + lv]; nb = bb[b2 + lv];
            nr = rr[b2 + lv]; nk = kk[b2 + lv]; nv = vv[b2 + lane];
        }

        // S = S*w + sa*b (+ v*k); accumulate local y/q partials
        float y0 = 0.f, y1 = 0.f, q0 = 0.f, q1 = 0.f;
        #pragma unroll
        for (int jj = 0; jj < 16; jj += 2) {
            const float w0 = rl(cw, jj), w1 = rl(cw, jj + 1);
            const float b0 = rl(cb, jj), b1 = rl(cb, jj + 1);
            const float k0 = rl(ck, jj), k1 = rl(ck, jj + 1);
            const float r0 = rl(cr, jj), r1 = rl(cr, jj + 1);
            SP[jj + 0] = SP[jj + 0] * w0 + saP * b0 + cv * k0;
            SP[jj + 1] = SP[jj + 1] * w1 + saP * b1 + cv * k1;
            SM[jj + 0] = SM[jj + 0] * w0 + saM * b0;
            SM[jj + 1] = SM[jj + 1] * w1 + saM * b1;
            y0 += SP[jj + 0] * r0;
            y1 += SP[jj + 1] * r1;
            q0 += SM[jj + 0] * r0;
            q1 += SM[jj + 1] * r1;
        }
        py = y0 + y1;
        pq = q0 + q1;

        base += HN;
        ca = na; cw = nw; cb = nb; cr = nr; ck = nk; cv = nv;
    }

    // drain the deferred outputs of the final step
    {
        const int p = (Ll - 1) & 1;
        exy[p][wv][lane] = py;
        exq[p][wv][lane] = pq;
        __syncthreads();
        const int ob = base - HN + lane;
        if (wv == 0) {
            ylocal[ob] = (exy[p][0][lane] + exy[p][1][lane])
                       + (exy[p][2][lane] + exy[p][3][lane]);
        } else if (wv == 1) {
            stf(&rho[ob], (exq[p][0][lane] + exq[p][1][lane])
                        + (exq[p][2][lane] + exq[p][3][lane]));
        }
    }

    // chunk-final matrices, stored transposed: [c][h][col j][row lane]
    const size_t mb = ((size_t)(c * Hh) + h) * NN;
    #pragma unroll
    for (int jj = 0; jj < 16; ++jj) {
        stf(&Pt[mb + (size_t)(j0 + jj) * Nn + lane], SP[jj]);
        stf(&Mt[mb + (size_t)(j0 + jj) * Nn + lane], SM[jj]);
    }
}

// ---------------------------------------------------------------- pass 2
#define LMS 68   // LDS row stride (dwords): 64 + 4 pad -> conflict-free b128

template <typename ST>
__global__ __launch_bounds__(512, 2)
void pass2_chain(const ST* __restrict__ Mt, const ST* __restrict__ Pt,
                 const float* __restrict__ st0, ST* __restrict__ Sst,
                 float* __restrict__ sfin)
{
    // bid = g*32 + h  ->  bid%8 = h%8: all 8 row-groups of head h on ONE XCD
    const int bid = blockIdx.x;
    const int h   = bid & 31;
    const int g   = bid >> 5;
    const int tid = threadIdx.x;
    const int j   = tid & 63;          // column (lane)
    const int wv  = tid >> 6;          // wave 0..7
    const int r   = g * 8 + wv;        // row

    __shared__ float lm[2][Nn][LMS];   // [buf][col j][k] = M[k][j] (Mt row j)
    __shared__ float lpp[2][8][LMS];   // [buf][local row][col] = P[r][j]

    float s = st0[(h * Nn + r) * Nn + j];

    // P staging address: thread covers (local row = tid&7, col = tid>>3)
    const int pr = tid & 7, pc = tid >> 3;
    const size_t poff = (size_t)pc * Nn + g * 8 + pr;   // Pt[col*64 + row]

    // ---- stage chunk 0 into buffers 0 (coalesced global, LDS tiles)
    {
        const size_t mb = (size_t)h * NN;
        if constexpr (sizeof(ST) == 2) {
            const uint4 u = *(const uint4*)&Mt[mb + (size_t)tid * 8];
            const int jj = tid >> 3, kc = (tid & 7) * 8;
            float4 f0, f1;
            f0.x = bflo(u.x); f0.y = bfhi(u.x); f0.z = bflo(u.y); f0.w = bfhi(u.y);
            f1.x = bflo(u.z); f1.y = bfhi(u.z); f1.z = bflo(u.w); f1.w = bfhi(u.w);
            *(float4*)&lm[0][jj][kc]     = f0;
            *(float4*)&lm[0][jj][kc + 4] = f1;
        } else {
            const float4 q0 = *(const float4*)&Mt[mb + (size_t)tid * 4];
            const float4 q1 = *(const float4*)&Mt[mb + 2048 + (size_t)tid * 4];
            const int jj = tid >> 4, kc = (tid * 4) & 63;
            *(float4*)&lm[0][jj][kc]      = q0;
            *(float4*)&lm[0][32 + jj][kc] = q1;
        }
        lpp[0][pr][pc] = ldf(&Pt[mb + poff]);
    }
    __syncthreads();

    for (int c = 0; c < Cc; ++c) {
        const int buf = c & 1;
        // S_before[c] out (row-major [r][j], coalesced)
        stf(&Sst[((size_t)(c * Hh) + h) * NN + (size_t)r * Nn + j], s);

        // issue next chunk's stage loads early (latency hides under k-dot)
        const bool pf = (c + 1 < Cc);
        const size_t nb = ((size_t)((c + 1) * Hh) + h) * NN;
        uint4 u = {0, 0, 0, 0};
        float4 q0 = {0, 0, 0, 0}, q1 = {0, 0, 0, 0};
        float praw = 0.f;
        if (pf) {
            if constexpr (sizeof(ST) == 2) {
                u = *(const uint4*)&Mt[nb + (size_t)tid * 8];
            } else {
                q0 = *(const float4*)&Mt[nb + (size_t)tid * 4];
                q1 = *(const float4*)&Mt[nb + 2048 + (size_t)tid * 4];
            }
            praw = ldf(&Pt[nb + poff]);
        }

        // newS[r][j] = sum_k S[r][k] * M[k][j] + P[r][j]
        float a0 = lpp[buf][wv][j], a1 = 0.f, a2 = 0.f, a3 = 0.f;
        #pragma unroll
        for (int m = 0; m < 16; ++m) {
            const float4 mv = *(const float4*)&lm[buf][j][4 * m];
            a0 += rl(s, 4 * m + 0) * mv.x;
            a1 += rl(s, 4 * m + 1) * mv.y;
            a2 += rl(s, 4 * m + 2) * mv.z;
            a3 += rl(s, 4 * m + 3) * mv.w;
        }

        // write next chunk's tiles into the other buffer
        if (pf) {
            if constexpr (sizeof(ST) == 2) {
                const int jj = tid >> 3, kc = (tid & 7) * 8;
                float4 f0, f1;
                f0.x = bflo(u.x); f0.y = bfhi(u.x); f0.z = bflo(u.y); f0.w = bfhi(u.y);
                f1.x = bflo(u.z); f1.y = bfhi(u.z); f1.z = bflo(u.w); f1.w = bfhi(u.w);
                *(float4*)&lm[buf ^ 1][jj][kc]     = f0;
                *(float4*)&lm[buf ^ 1][jj][kc + 4] = f1;
            } else {
                const int jj = tid >> 4, kc = (tid * 4) & 63;
                *(float4*)&lm[buf ^ 1][jj][kc]      = q0;
                *(float4*)&lm[buf ^ 1][32 + jj][kc] = q1;
            }
            lpp[buf ^ 1][pr][pc] = praw;
        }

        s = (a0 + a1) + (a2 + a3);
        __syncthreads();
    }

    // final state -> d_out tail (fp32)
    sfin[(h * Nn + r) * Nn + j] = s;
}

// ---------------------------------------------------------------- pass 3
template <typename ST>
__global__ __launch_bounds__(256, 4)
void pass3_fix(const ST* __restrict__ rho, const ST* __restrict__ Sst,
               float* __restrict__ y)
{
    const int c    = blockIdx.x >> 5;   // chunk
    const int h    = blockIdx.x & 31;   // head
    const int tid  = threadIdx.x;
    const int lane = tid & 63;          // output row i
    const int tq   = tid >> 6;          // wave 0..3, handles t = tq*16 + m

    __shared__ float ls[Nn][LMS];       // [row i][col k] = S_before[c][h]

    // stage S tile (row-major in Sst) coalesced -> LDS
    const size_t sb = ((size_t)(c * Hh) + h) * NN;
    if constexpr (sizeof(ST) == 2) {
        #pragma unroll
        for (int half = 0; half < 2; ++half) {
            const int e = half * 2048 + tid * 8;
            const uint4 u = *(const uint4*)&Sst[sb + e];
            const int jj = e >> 6, kc = e & 63;
            float4 f0, f1;
            f0.x = bflo(u.x); f0.y = bfhi(u.x); f0.z = bflo(u.y); f0.w = bfhi(u.y);
            f1.x = bflo(u.z); f1.y = bfhi(u.z); f1.z = bflo(u.w); f1.w = bfhi(u.w);
            *(float4*)&ls[jj][kc]     = f0;
            *(float4*)&ls[jj][kc + 4] = f1;
        }
    } else {
        #pragma unroll
        for (int qq = 0; qq < 4; ++qq) {
            const int e = qq * 1024 + tid * 4;
            const float4 v = *(const float4*)&Sst[sb + e];
            *(float4*)&ls[e >> 6][e & 63] = v;
        }
    }

    // each wave's 16 rho rows, lane-distributed: rt[m] = rho[t][h][lane]
    float rt[16];
    #pragma unroll
    for (int m = 0; m < 16; ++m)
        rt[m] = ldf(&rho[((size_t)(c * Ll + tq * 16 + m) * Hh + h) * Nn + lane]);

    __syncthreads();

    float Srow[Nn];  // S_before[c][h] row `lane` (conflict-free b128 from LDS)
    #pragma unroll
    for (int m = 0; m < 16; ++m) {
        const float4 v = *(const float4*)&ls[lane][4 * m];
        Srow[4*m+0] = v.x; Srow[4*m+1] = v.y; Srow[4*m+2] = v.z; Srow[4*m+3] = v.w;
    }

    #pragma unroll
    for (int m = 0; m < 16; ++m) {
        float a0 = 0.f, a1 = 0.f, a2 = 0.f, a3 = 0.f;
        #pragma unroll
        for (int j = 0; j < Nn; j += 4) {
            a0 += rl(rt[m], j + 0) * Srow[j + 0];
            a1 += rl(rt[m], j + 1) * Srow[j + 1];
            a2 += rl(rt[m], j + 2) * Srow[j + 2];
            a3 += rl(rt[m], j + 3) * Srow[j + 3];
        }
        const size_t oy = ((size_t)(c * Ll + tq * 16 + m) * Hh + h) * Nn + lane;
        y[oy] = y[oy] + ((a0 + a1) + (a2 + a3));
    }
}

// ------------------------------------------- zero-scratch sequential fallback
__global__ __launch_bounds__(64, 1)
void seq_scan(const float* __restrict__ rr, const float* __restrict__ ww,
              const float* __restrict__ kk, const float* __restrict__ vv,
              const float* __restrict__ aa, const float* __restrict__ bb,
              const float* __restrict__ st0,
              float* __restrict__ y, float* __restrict__ sfin)
{
    const int h    = blockIdx.x;
    const int lane = threadIdx.x;          // row i

    float S[Nn];
    #pragma unroll
    for (int j = 0; j < Nn; ++j) S[j] = st0[(h * Nn + lane) * Nn + j];

    int base = h * Nn;
    float ca = aa[base + lane], cw = ww[base + lane], cb = bb[base + lane];
    float cr = rr[base + lane], ck = kk[base + lane], cv = vv[base + lane];

    for (int t = 0; t < Tt; ++t) {
        float na = 0.f, nw = 0.f, nb = 0.f, nr = 0.f, nk = 0.f, nv = 0.f;
        if (t + 1 < Tt) {
            const int b2 = base + HN + lane;
            na = aa[b2]; nw = ww[b2]; nb = bb[b2];
            nr = rr[b2]; nk = kk[b2]; nv = vv[b2];
        }

        float s0 = 0.f, s1 = 0.f;
        #pragma unroll
        for (int j = 0; j < Nn; j += 2) {
            s0 += S[j + 0] * rl(ca, j);
            s1 += S[j + 1] * rl(ca, j + 1);
        }
        const float sa = s0 + s1;

        float y0 = 0.f, y1 = 0.f;
        #pragma unroll
        for (int j = 0; j < Nn; j += 2) {
            const float w0 = rl(cw, j), w1 = rl(cw, j + 1);
            const float b0 = rl(cb, j), b1 = rl(cb, j + 1);
            const float k0 = rl(ck, j), k1 = rl(ck, j + 1);
            const float r0 = rl(cr, j), r1 = rl(cr, j + 1);
            S[j + 0] = S[j + 0] * w0 + sa * b0 + cv * k0;
            S[j + 1] = S[j + 1] * w1 + sa * b1 + cv * k1;
            y0 += S[j + 0] * r0;
            y1 += S[j + 1] * r1;
        }
        y[base + lane] = y0 + y1;
        base += HN;
        ca = na; cw = nw; cb = nb; cr = nr; ck = nk; cv = nv;
    }

    #pragma unroll
    for (int j = 0; j < Nn; ++j) sfin[(h * Nn + lane) * Nn + j] = S[j];
}

// ---------------------------------------------------------------- launch
extern "C" void kernel_launch(void* const* d_in, const int* in_sizes, int n_in,
                              void* d_out, int out_size, void* d_ws, size_t ws_size,
                              hipStream_t stream)
{
    const float* r  = (const float*)d_in[0];
    const float* w  = (const float*)d_in[1];
    const float* k  = (const float*)d_in[2];
    const float* v  = (const float*)d_in[3];
    const float* a  = (const float*)d_in[4];
    const float* b  = (const float*)d_in[5];
    const float* st = (const float*)d_in[6];

    float* out  = (float*)d_out;
    float* yl   = out;                       // y region (also y_local scratch)
    float* sfin = out + (size_t)Tt * HN;     // S_final region

    const size_t nTHN = (size_t)Tt * HN;       // 8388608 (rho)
    const size_t nCH  = (size_t)Cc * Hh * NN;  // 8388608 (each of Mt, Pt, Sst)
    const size_t need = nTHN + 3 * nCH;        // scratch element count

    if (ws_size >= need * sizeof(float)) {
        float* ws  = (float*)d_ws;
        float* rho = ws;
        float* Mt  = ws + nTHN;
        float* Pt  = Mt + nCH;
        float* Ss  = Pt + nCH;
        hipLaunchKernelGGL((pass1_scan<float>), dim3(Cc * Hh), dim3(256), 0, stream,
                           r, w, k, v, a, b, yl, rho, Mt, Pt);
        hipLaunchKernelGGL((pass2_chain<float>), dim3(Hh * 8), dim3(512), 0, stream,
                           Mt, Pt, st, Ss, sfin);
        hipLaunchKernelGGL((pass3_fix<float>), dim3(Cc * Hh), dim3(256), 0, stream,
                           rho, Ss, out);
    } else if (ws_size >= need * sizeof(__hip_bfloat16)) {
        __hip_bfloat16* ws  = (__hip_bfloat16*)d_ws;
        __hip_bfloat16* rho = ws;
        __hip_bfloat16* Mt  = ws + nTHN;
        __hip_bfloat16* Pt  = Mt + nCH;
        __hip_bfloat16* Ss  = Pt + nCH;
        hipLaunchKernelGGL((pass1_scan<__hip_bfloat16>), dim3(Cc * Hh), dim3(256), 0, stream,
                           r, w, k, v, a, b, yl, rho, Mt, Pt);
        hipLaunchKernelGGL((pass2_chain<__hip_bfloat16>), dim3(Hh * 8), dim3(512), 0, stream,
                           Mt, Pt, st, Ss, sfin);
        hipLaunchKernelGGL((pass3_fix<__hip_bfloat16>), dim3(Cc * Hh), dim3(256), 0, stream,
                           rho, Ss, out);
    } else {
        // no usable scratch: correct-but-slow sequential scan
        hipLaunchKernelGGL(seq_scan, dim3(Hh), dim3(64), 0, stream,
                           r, w, k, v, a, b, st, yl, sfin);
    }
}

// Round 6
// 423.708 us; speedup vs baseline: 1.1996x; 1.1996x over previous
//
#include <hip/hip_runtime.h>
#include <hip/hip_bf16.h>

// RWKV7 WKV chunked scan. T=4096, H=32, N=64. Output fp32 (y then S_final).
//
// Pass 1 (R10): back to R5's TWO-wave column-split (R9's 4-wave split grew
//   total instructions and regressed — pass1 is ISSUE-bound, not latency-
//   bound). New: the P and M scans are PACKED into f32x2 (v_pk_fma_f32):
//   SPM[j] = {SP[j], SM[j]} shares every w/b/r/a broadcast; per-column work
//   drops 14 -> 10 issue slots. Exchange via double-buffered LDS, ONE barrier
//   per step; readlane broadcasts with inline-constant lane index.
// Pass 2 (R10): 256-thread blocks (4 rows each), grid 512 = 2 blocks/CU so
//   one block's per-chunk barrier stalls overlap the other's compute.
//   M staged via LDS (stride 68, conflict-free b128), double-buffered;
//   P staged via LDS (lpp). All global accesses coalesced (R6 lesson:
//   per-lane-strided global loads pay a ~10x address-divergence tax).
// Pass 3 (R8): S_before tile staged through LDS (pad 68), Srow via b128;
//   rho rows coalesced + readlane; y RMW coalesced.

#define Tt 4096
#define Hh 32
#define Nn 64
#define Ll 64              // chunk length
#define Cc 64              // number of chunks
#define HN (Hh * Nn)       // 2048
#define NN (Nn * Nn)       // 4096

typedef __attribute__((ext_vector_type(2))) float f32x2;

__device__ __forceinline__ float ldf(const float* p) { return *p; }
__device__ __forceinline__ float ldf(const __hip_bfloat16* p) { return __bfloat162float(*p); }
__device__ __forceinline__ void stf(float* p, float v) { *p = v; }
__device__ __forceinline__ void stf(__hip_bfloat16* p, float v) { *p = __float2bfloat16(v); }

__device__ __forceinline__ float rl(float v, int j) {
    return __int_as_float(__builtin_amdgcn_readlane(__float_as_int(v), j));
}

// unpack a uint (2 bf16) into two floats, elem0 = low 16 bits
__device__ __forceinline__ float bflo(unsigned u) { return __uint_as_float(u << 16); }
__device__ __forceinline__ float bfhi(unsigned u) { return __uint_as_float(u & 0xffff0000u); }

// ---------------------------------------------------------------- pass 1
template <typename ST>
__global__ __launch_bounds__(128, 4)
void pass1_scan(const float* __restrict__ rr, const float* __restrict__ ww,
                const float* __restrict__ kk, const float* __restrict__ vv,
                const float* __restrict__ aa, const float* __restrict__ bb,
                float* __restrict__ ylocal,
                ST* __restrict__ rho, ST* __restrict__ Mt, ST* __restrict__ Pt)
{
    const int c    = blockIdx.x >> 5;      // chunk
    const int h    = blockIdx.x & 31;      // head
    const int tid  = threadIdx.x;
    const int lane = tid & 63;             // row i
    const int wv   = tid >> 6;             // column-half 0/1
    const int j0   = __builtin_amdgcn_readfirstlane(wv << 5);

    // partial-exchange buffers, double-buffered over step parity
    __shared__ f32x2 ex1[2][2][64];        // [par][wave][row] = {saP, saM} partials
    __shared__ f32x2 exy[2][2][64];        // [par][wave][row] = {y, q} partials

    f32x2 SPM[32];                         // {P, M} scan state, local columns
    #pragma unroll
    for (int jj = 0; jj < 32; ++jj) {
        f32x2 ini; ini.x = 0.0f; ini.y = (j0 + jj == lane) ? 1.0f : 0.0f;
        SPM[jj] = ini;
    }

    int base = (c * Ll * Hh + h) * Nn;     // element offset of step t
    const int lv = j0 + (lane & 31);       // broadcast-source element this lane carries
    float ca = aa[base + lv];
    float cw = ww[base + lv];
    float cb = bb[base + lv];
    float cr = rr[base + lv];
    float ck = kk[base + lv];
    float cv = vv[base + lane];            // per-row value (full vector per lane)

    f32x2 pyq = {0.f, 0.f};                // {y,q} partials of step t-1

    for (int t = 0; t < Ll; ++t) {
        // partial sa over local columns, packed {P,M}
        f32x2 pm0 = {0.f, 0.f}, pm1 = {0.f, 0.f};
        #pragma unroll
        for (int jj = 0; jj < 32; jj += 2) {
            const float a0 = rl(ca, jj), a1 = rl(ca, jj + 1);
            pm0 += SPM[jj + 0] * a0;
            pm1 += SPM[jj + 1] * a1;
        }
        const f32x2 pm = pm0 + pm1;

        ex1[t & 1][wv][lane] = pm;
        if (t > 0) exy[(t - 1) & 1][wv][lane] = pyq;
        __syncthreads();
        const f32x2 o  = ex1[t & 1][wv ^ 1][lane];
        const f32x2 sa2 = pm + o;          // {saP, saM}
        if (t > 0) {                        // finish + store step t-1 outputs
            const f32x2 oy = exy[(t - 1) & 1][wv ^ 1][lane];
            const int ob = base - HN + lane;
            if (wv == 0) ylocal[ob] = pyq.x + oy.x;
            else         stf(&rho[ob], pyq.y + oy.y);
        }

        // prefetch next step's vectors (uniform branch; hides under update loop)
        float na = 0.f, nw = 0.f, nb = 0.f, nr = 0.f, nk = 0.f, nv = 0.f;
        if (t + 1 < Ll) {
            const int b2 = base + HN;
            na = aa[b2 + lv]; nw = ww[b2 + lv]; nb = bb[b2 + lv];
            nr = rr[b2 + lv]; nk = kk[b2 + lv]; nv = vv[b2 + lane];
        }

        // SPM = SPM*w + sa2*b (+ {v*k, 0}); accumulate local {y,q} partials
        f32x2 yq0 = {0.f, 0.f}, yq1 = {0.f, 0.f};
        #pragma unroll
        for (int jj = 0; jj < 32; jj += 2) {
            const float w0 = rl(cw, jj), w1 = rl(cw, jj + 1);
            const float b0 = rl(cb, jj), b1 = rl(cb, jj + 1);
            const float k0 = rl(ck, jj), k1 = rl(ck, jj + 1);
            const float r0 = rl(cr, jj), r1 = rl(cr, jj + 1);
            f32x2 t0 = SPM[jj + 0] * w0 + sa2 * b0;
            f32x2 t1 = SPM[jj + 1] * w1 + sa2 * b1;
            t0.x += cv * k0;
            t1.x += cv * k1;
            SPM[jj + 0] = t0;
            SPM[jj + 1] = t1;
            yq0 += t0 * r0;
            yq1 += t1 * r1;
        }
        pyq = yq0 + yq1;

        base += HN;
        ca = na; cw = nw; cb = nb; cr = nr; ck = nk; cv = nv;
    }

    // drain the deferred outputs of the final step
    {
        const int p = (Ll - 1) & 1;
        exy[p][wv][lane] = pyq;
        __syncthreads();
        const f32x2 oy = exy[p][wv ^ 1][lane];
        const int ob = base - HN + lane;
        if (wv == 0) ylocal[ob] = pyq.x + oy.x;
        else         stf(&rho[ob], pyq.y + oy.y);
    }

    // chunk-final matrices, stored transposed: [c][h][col j][row lane]
    const size_t mb = ((size_t)(c * Hh) + h) * NN;
    #pragma unroll
    for (int jj = 0; jj < 32; ++jj) {
        stf(&Pt[mb + (size_t)(j0 + jj) * Nn + lane], SPM[jj].x);
        stf(&Mt[mb + (size_t)(j0 + jj) * Nn + lane], SPM[jj].y);
    }
}

// ---------------------------------------------------------------- pass 2
#define LMS 68   // LDS row stride (dwords): 64 + 4 pad -> conflict-free b128

template <typename ST>
__global__ __launch_bounds__(256, 4)
void pass2_chain(const ST* __restrict__ Mt, const ST* __restrict__ Pt,
                 const float* __restrict__ st0, ST* __restrict__ Sst,
                 float* __restrict__ sfin)
{
    // bid = g*32 + h: h%8 fixes the XCD group for all 16 row-groups of head h
    const int bid = blockIdx.x;
    const int h   = bid & 31;
    const int g   = bid >> 5;          // 0..15 row-group
    const int tid = threadIdx.x;
    const int j   = tid & 63;          // column (lane)
    const int wv  = tid >> 6;          // wave 0..3 (local row)
    const int r   = g * 4 + wv;        // global row

    __shared__ float lm[2][Nn][LMS];   // [buf][col j][k] = M[k][j] (Mt row j)
    __shared__ float lpp[2][4][LMS];   // [buf][local row][col] = P[r][j]

    float s = st0[(h * Nn + r) * Nn + j];

    // P staging address: thread covers (local row = tid&3, col = tid>>2)
    const int pr = tid & 3, pc = tid >> 2;
    const size_t poff = (size_t)pc * Nn + g * 4 + pr;   // Pt[col*64 + row]

    // ---- stage chunk 0 into buffers 0 (coalesced global, LDS tiles)
    {
        const size_t mb = (size_t)h * NN;
        if constexpr (sizeof(ST) == 2) {
            #pragma unroll
            for (int half = 0; half < 2; ++half) {
                const int e = half * 2048 + tid * 8;
                const uint4 u = *(const uint4*)&Mt[mb + e];
                const int jj = e >> 6, kc = e & 63;
                float4 f0, f1;
                f0.x = bflo(u.x); f0.y = bfhi(u.x); f0.z = bflo(u.y); f0.w = bfhi(u.y);
                f1.x = bflo(u.z); f1.y = bfhi(u.z); f1.z = bflo(u.w); f1.w = bfhi(u.w);
                *(float4*)&lm[0][jj][kc]     = f0;
                *(float4*)&lm[0][jj][kc + 4] = f1;
            }
        } else {
            #pragma unroll
            for (int qq = 0; qq < 4; ++qq) {
                const int e = qq * 1024 + tid * 4;
                const float4 q0 = *(const float4*)&Mt[mb + e];
                *(float4*)&lm[0][e >> 6][e & 63] = q0;
            }
        }
        lpp[0][pr][pc] = ldf(&Pt[mb + poff]);
    }
    __syncthreads();

    for (int c = 0; c < Cc; ++c) {
        const int buf = c & 1;
        // S_before[c] out (row-major [r][j], coalesced)
        stf(&Sst[((size_t)(c * Hh) + h) * NN + (size_t)r * Nn + j], s);

        // issue next chunk's stage loads early (latency hides under k-dot)
        const bool pf = (c + 1 < Cc);
        const size_t nb = ((size_t)((c + 1) * Hh) + h) * NN;
        uint4 u0 = {0,0,0,0}, u1 = {0,0,0,0};
        float4 q0 = {0,0,0,0}, q1 = {0,0,0,0}, q2 = {0,0,0,0}, q3 = {0,0,0,0};
        float praw = 0.f;
        if (pf) {
            if constexpr (sizeof(ST) == 2) {
                u0 = *(const uint4*)&Mt[nb + tid * 8];
                u1 = *(const uint4*)&Mt[nb + 2048 + tid * 8];
            } else {
                q0 = *(const float4*)&Mt[nb + tid * 4];
                q1 = *(const float4*)&Mt[nb + 1024 + tid * 4];
                q2 = *(const float4*)&Mt[nb + 2048 + tid * 4];
                q3 = *(const float4*)&Mt[nb + 3072 + tid * 4];
            }
            praw = ldf(&Pt[nb + poff]);
        }

        // newS[r][j] = sum_k S[r][k] * M[k][j] + P[r][j]
        float a0 = lpp[buf][wv][j], a1 = 0.f, a2 = 0.f, a3 = 0.f;
        #pragma unroll
        for (int m = 0; m < 16; ++m) {
            const float4 mv = *(const float4*)&lm[buf][j][4 * m];
            a0 += rl(s, 4 * m + 0) * mv.x;
            a1 += rl(s, 4 * m + 1) * mv.y;
            a2 += rl(s, 4 * m + 2) * mv.z;
            a3 += rl(s, 4 * m + 3) * mv.w;
        }

        // write next chunk's tiles into the other buffer
        if (pf) {
            if constexpr (sizeof(ST) == 2) {
                {
                    const int e = tid * 8, jj = e >> 6, kc = e & 63;
                    float4 f0, f1;
                    f0.x = bflo(u0.x); f0.y = bfhi(u0.x); f0.z = bflo(u0.y); f0.w = bfhi(u0.y);
                    f1.x = bflo(u0.z); f1.y = bfhi(u0.z); f1.z = bflo(u0.w); f1.w = bfhi(u0.w);
                    *(float4*)&lm[buf ^ 1][jj][kc]     = f0;
                    *(float4*)&lm[buf ^ 1][jj][kc + 4] = f1;
                }
                {
                    const int e = 2048 + tid * 8, jj = e >> 6, kc = e & 63;
                    float4 f0, f1;
                    f0.x = bflo(u1.x); f0.y = bfhi(u1.x); f0.z = bflo(u1.y); f0.w = bfhi(u1.y);
                    f1.x = bflo(u1.z); f1.y = bfhi(u1.z); f1.z = bflo(u1.w); f1.w = bfhi(u1.w);
                    *(float4*)&lm[buf ^ 1][jj][kc]     = f0;
                    *(float4*)&lm[buf ^ 1][jj][kc + 4] = f1;
                }
            } else {
                const int e0 = tid * 4;
                *(float4*)&lm[buf ^ 1][e0 >> 6][e0 & 63] = q0;
                const int e1 = 1024 + tid * 4;
                *(float4*)&lm[buf ^ 1][e1 >> 6][e1 & 63] = q1;
                const int e2 = 2048 + tid * 4;
                *(float4*)&lm[buf ^ 1][e2 >> 6][e2 & 63] = q2;
                const int e3 = 3072 + tid * 4;
                *(float4*)&lm[buf ^ 1][e3 >> 6][e3 & 63] = q3;
            }
            lpp[buf ^ 1][pr][pc] = praw;
        }

        s = (a0 + a1) + (a2 + a3);
        __syncthreads();
    }

    // final state -> d_out tail (fp32)
    sfin[(h * Nn + r) * Nn + j] = s;
}

// ---------------------------------------------------------------- pass 3
template <typename ST>
__global__ __launch_bounds__(256, 4)
void pass3_fix(const ST* __restrict__ rho, const ST* __restrict__ Sst,
               float* __restrict__ y)
{
    const int c    = blockIdx.x >> 5;   // chunk
    const int h    = blockIdx.x & 31;   // head
    const int tid  = threadIdx.x;
    const int lane = tid & 63;          // output row i
    const int tq   = tid >> 6;          // wave 0..3, handles t = tq*16 + m

    __shared__ float ls[Nn][LMS];       // [row i][col k] = S_before[c][h]

    // stage S tile (row-major in Sst) coalesced -> LDS
    const size_t sb = ((size_t)(c * Hh) + h) * NN;
    if constexpr (sizeof(ST) == 2) {
        #pragma unroll
        for (int half = 0; half < 2; ++half) {
            const int e = half * 2048 + tid * 8;
            const uint4 u = *(const uint4*)&Sst[sb + e];
            const int jj = e >> 6, kc = e & 63;
            float4 f0, f1;
            f0.x = bflo(u.x); f0.y = bfhi(u.x); f0.z = bflo(u.y); f0.w = bfhi(u.y);
            f1.x = bflo(u.z); f1.y = bfhi(u.z); f1.z = bflo(u.w); f1.w = bfhi(u.w);
            *(float4*)&ls[jj][kc]     = f0;
            *(float4*)&ls[jj][kc + 4] = f1;
        }
    } else {
        #pragma unroll
        for (int qq = 0; qq < 4; ++qq) {
            const int e = qq * 1024 + tid * 4;
            const float4 v = *(const float4*)&Sst[sb + e];
            *(float4*)&ls[e >> 6][e & 63] = v;
        }
    }

    // each wave's 16 rho rows, lane-distributed: rt[m] = rho[t][h][lane]
    float rt[16];
    #pragma unroll
    for (int m = 0; m < 16; ++m)
        rt[m] = ldf(&rho[((size_t)(c * Ll + tq * 16 + m) * Hh + h) * Nn + lane]);

    __syncthreads();

    float Srow[Nn];  // S_before[c][h] row `lane` (conflict-free b128 from LDS)
    #pragma unroll
    for (int m = 0; m < 16; ++m) {
        const float4 v = *(const float4*)&ls[lane][4 * m];
        Srow[4*m+0] = v.x; Srow[4*m+1] = v.y; Srow[4*m+2] = v.z; Srow[4*m+3] = v.w;
    }

    #pragma unroll
    for (int m = 0; m < 16; ++m) {
        float a0 = 0.f, a1 = 0.f, a2 = 0.f, a3 = 0.f;
        #pragma unroll
        for (int j = 0; j < Nn; j += 4) {
            a0 += rl(rt[m], j + 0) * Srow[j + 0];
            a1 += rl(rt[m], j + 1) * Srow[j + 1];
            a2 += rl(rt[m], j + 2) * Srow[j + 2];
            a3 += rl(rt[m], j + 3) * Srow[j + 3];
        }
        const size_t oy = ((size_t)(c * Ll + tq * 16 + m) * Hh + h) * Nn + lane;
        y[oy] = y[oy] + ((a0 + a1) + (a2 + a3));
    }
}

// ------------------------------------------- zero-scratch sequential fallback
__global__ __launch_bounds__(64, 1)
void seq_scan(const float* __restrict__ rr, const float* __restrict__ ww,
              const float* __restrict__ kk, const float* __restrict__ vv,
              const float* __restrict__ aa, const float* __restrict__ bb,
              const float* __restrict__ st0,
              float* __restrict__ y, float* __restrict__ sfin)
{
    const int h    = blockIdx.x;
    const int lane = threadIdx.x;          // row i

    float S[Nn];
    #pragma unroll
    for (int j = 0; j < Nn; ++j) S[j] = st0[(h * Nn + lane) * Nn + j];

    int base = h * Nn;
    float ca = aa[base + lane], cw = ww[base + lane], cb = bb[base + lane];
    float cr = rr[base + lane], ck = kk[base + lane], cv = vv[base + lane];

    for (int t = 0; t < Tt; ++t) {
        float na = 0.f, nw = 0.f, nb = 0.f, nr = 0.f, nk = 0.f, nv = 0.f;
        if (t + 1 < Tt) {
            const int b2 = base + HN + lane;
            na = aa[b2]; nw = ww[b2]; nb = bb[b2];
            nr = rr[b2]; nk = kk[b2]; nv = vv[b2];
        }

        float s0 = 0.f, s1 = 0.f;
        #pragma unroll
        for (int j = 0; j < Nn; j += 2) {
            s0 += S[j + 0] * rl(ca, j);
            s1 += S[j + 1] * rl(ca, j + 1);
        }
        const float sa = s0 + s1;

        float y0 = 0.f, y1 = 0.f;
        #pragma unroll
        for (int j = 0; j < Nn; j += 2) {
            const float w0 = rl(cw, j), w1 = rl(cw, j + 1);
            const float b0 = rl(cb, j), b1 = rl(cb, j + 1);
            const float k0 = rl(ck, j), k1 = rl(ck, j + 1);
            const float r0 = rl(cr, j), r1 = rl(cr, j + 1);
            S[j + 0] = S[j + 0] * w0 + sa * b0 + cv * k0;
            S[j + 1] = S[j + 1] * w1 + sa * b1 + cv * k1;
            y0 += S[j + 0] * r0;
            y1 += S[j + 1] * r1;
        }
        y[base + lane] = y0 + y1;
        base += HN;
        ca = na; cw = nw; cb = nb; cr = nr; ck = nk; cv = nv;
    }

    #pragma unroll
    for (int j = 0; j < Nn; ++j) sfin[(h * Nn + lane) * Nn + j] = S[j];
}

// ---------------------------------------------------------------- launch
extern "C" void kernel_launch(void* const* d_in, const int* in_sizes, int n_in,
                              void* d_out, int out_size, void* d_ws, size_t ws_size,
                              hipStream_t stream)
{
    const float* r  = (const float*)d_in[0];
    const float* w  = (const float*)d_in[1];
    const float* k  = (const float*)d_in[2];
    const float* v  = (const float*)d_in[3];
    const float* a  = (const float*)d_in[4];
    const float* b  = (const float*)d_in[5];
    const float* st = (const float*)d_in[6];

    float* out  = (float*)d_out;
    float* yl   = out;                       // y region (also y_local scratch)
    float* sfin = out + (size_t)Tt * HN;     // S_final region

    const size_t nTHN = (size_t)Tt * HN;       // 8388608 (rho)
    const size_t nCH  = (size_t)Cc * Hh * NN;  // 8388608 (each of Mt, Pt, Sst)
    const size_t need = nTHN + 3 * nCH;        // scratch element count

    if (ws_size >= need * sizeof(float)) {
        float* ws  = (float*)d_ws;
        float* rho = ws;
        float* Mt  = ws + nTHN;
        float* Pt  = Mt + nCH;
        float* Ss  = Pt + nCH;
        hipLaunchKernelGGL((pass1_scan<float>), dim3(Cc * Hh), dim3(128), 0, stream,
                           r, w, k, v, a, b, yl, rho, Mt, Pt);
        hipLaunchKernelGGL((pass2_chain<float>), dim3(Hh * 16), dim3(256), 0, stream,
                           Mt, Pt, st, Ss, sfin);
        hipLaunchKernelGGL((pass3_fix<float>), dim3(Cc * Hh), dim3(256), 0, stream,
                           rho, Ss, out);
    } else if (ws_size >= need * sizeof(__hip_bfloat16)) {
        __hip_bfloat16* ws  = (__hip_bfloat16*)d_ws;
        __hip_bfloat16* rho = ws;
        __hip_bfloat16* Mt  = ws + nTHN;
        __hip_bfloat16* Pt  = Mt + nCH;
        __hip_bfloat16* Ss  = Pt + nCH;
        hipLaunchKernelGGL((pass1_scan<__hip_bfloat16>), dim3(Cc * Hh), dim3(128), 0, stream,
                           r, w, k, v, a, b, yl, rho, Mt, Pt);
        hipLaunchKernelGGL((pass2_chain<__hip_bfloat16>), dim3(Hh * 16), dim3(256), 0, stream,
                           Mt, Pt, st, Ss, sfin);
        hipLaunchKernelGGL((pass3_fix<__hip_bfloat16>), dim3(Cc * Hh), dim3(256), 0, stream,
                           rho, Ss, out);
    } else {
        // no usable scratch: correct-but-slow sequential scan
        hipLaunchKernelGGL(seq_scan, dim3(Hh), dim3(64), 0, stream,
                           r, w, k, v, a, b, st, yl, sfin);
    }
}